// Round 1
// baseline (1904.729 us; speedup 1.0000x reference)
//
#include <hip/hip_runtime.h>
#include <hip/hip_bf16.h>

// Problem constants (match the reference).
#define BB 256
#define TT 2048
#define FF 64
#define UU 64
#define C3 192   // 3*U

__device__ __forceinline__ float readlane_f(float v, int lane) {
    return __int_as_float(__builtin_amdgcn_readlane(__float_as_int(v), lane));
}

// sigmoid(x) = 1/(1+e^-x); rcp approx (~1 ulp) is far inside the 2e-2 threshold.
__device__ __forceinline__ float fast_sigmoid(float x) {
    float e = __expf(-x);
    return __builtin_amdgcn_rcpf(1.0f + e);
}
// tanh(x) = 1 - 2/(e^{2x}+1); correct limits at +-inf.
__device__ __forceinline__ float fast_tanh(float x) {
    float e2 = __expf(2.0f * x);
    return 1.0f - 2.0f * __builtin_amdgcn_rcpf(e2 + 1.0f);
}

// ---------------------------------------------------------------------------
// Kernel 1: x_proj chunk = inputs[:, t0:t0+tc, :] @ kernel + bias0 (+bz,br fold)
// Layout of xp: [B][tc][192] rows r = b*tc + tt.
// Each lane holds 3 kernel columns in registers; input row broadcast by readlane.
// ---------------------------------------------------------------------------
__global__ __launch_bounds__(256, 2)
void xproj_kernel(const float* __restrict__ in, const float* __restrict__ kmat,
                  const float* __restrict__ bias, float* __restrict__ xp,
                  int t0, int tc) {
    const int lane = threadIdx.x & 63;
    const int wave = (int)((blockIdx.x * blockDim.x + threadIdx.x) >> 6);
    const int nwaves = (int)((gridDim.x * blockDim.x) >> 6);

    float kz[64], kr[64], kh[64];
#pragma unroll
    for (int f = 0; f < 64; ++f) {
        kz[f] = kmat[f * C3 + lane];
        kr[f] = kmat[f * C3 + 64 + lane];
        kh[f] = kmat[f * C3 + 128 + lane];
    }
    // Fold bias0 (all gates) and bias1 for z,r. bias1_h (bh) stays in the scan
    // kernel because reset_after=True puts it inside r*(...).
    const float bz  = bias[lane]       + bias[C3 + lane];
    const float br  = bias[64 + lane]  + bias[C3 + 64 + lane];
    const float bh0 = bias[128 + lane];

    const int rows = BB * tc;
    for (int r = wave; r < rows; r += nwaves) {
        const int b  = r / tc;
        const int t  = t0 + (r - b * tc);
        const float a = in[((size_t)b * TT + t) * FF + lane];
        float az = bz, ar = br, ah = bh0;
#pragma unroll
        for (int f = 0; f < 64; ++f) {
            const float s = readlane_f(a, f);
            az = fmaf(s, kz[f], az);
            ar = fmaf(s, kr[f], ar);
            ah = fmaf(s, kh[f], ah);
        }
        float* o = xp + (size_t)r * C3;
        o[lane] = az; o[64 + lane] = ar; o[128 + lane] = ah;
    }
}

// ---------------------------------------------------------------------------
// Kernel 2: the serial GRU scan. One wave (64 lanes) per batch element.
// Lane j owns unit j. U columns in registers, masks folded in (exact: mask in
// {0,2}). Inner loop: 1 readlane + 3 FMA per i.
// FUSED_X=true computes x on the fly (fallback when d_ws is too small).
// ---------------------------------------------------------------------------
template <bool FUSED_X>
__global__ __launch_bounds__(64, 1)
void gru_kernel(const float* __restrict__ xp,   // chunk [B][tc][192] (!FUSED_X)
                const float* __restrict__ in,   // raw inputs (FUSED_X)
                const float* __restrict__ kmat, // (FUSED_X)
                const float* __restrict__ rk, const float* __restrict__ bias,
                const float* __restrict__ mask, const float* __restrict__ dw,
                const float* __restrict__ db, float* __restrict__ hws,
                float* __restrict__ out, int t0, int tc, int first, int last) {
    const int b = blockIdx.x;
    const int j = threadIdx.x;

    __shared__ float k_lds[FUSED_X ? (64 * C3) : 1];
    if (FUSED_X) {
        for (int idx = j; idx < 64 * C3; idx += 64) k_lds[idx] = kmat[idx];
        __syncthreads();
    }

    // Recurrent kernel columns for unit j, masks folded (time-constant).
    float uz[64], ur[64], uh[64];
#pragma unroll
    for (int i = 0; i < 64; ++i) {
        uz[i] = rk[i * C3 + j];
        ur[i] = rk[i * C3 + 64 + j];
        uh[i] = rk[i * C3 + 128 + j];
    }
    const float mz = mask[(size_t)b * UU + j];
    const float mr = mask[(size_t)BB * UU + (size_t)b * UU + j];
    const float mh = mask[2 * (size_t)BB * UU + (size_t)b * UU + j];
#pragma unroll
    for (int i = 0; i < 64; ++i) {
        uz[i] *= readlane_f(mz, i);
        ur[i] *= readlane_f(mr, i);
        uh[i] *= readlane_f(mh, i);
    }
    const float bh = bias[C3 + 128 + j];
    // Fused-path biases (otherwise already folded into xp).
    const float bzf  = bias[j] + bias[C3 + j];
    const float brf  = bias[64 + j] + bias[C3 + 64 + j];
    const float bh0f = bias[128 + j];

    float h = 0.0f;
    if (!first) h = hws[(size_t)b * UU + j];

    const float* xpb = xp + (size_t)b * tc * C3;

    // Prefetch t=0 inputs.
    float xz, xr, xh, a0;
    if (!FUSED_X) {
        xz = xpb[j]; xr = xpb[64 + j]; xh = xpb[128 + j];
    } else {
        a0 = in[((size_t)b * TT + t0) * FF + j];
    }

#pragma unroll 1
    for (int t = 0; t < tc; ++t) {
        // Prefetch next step's x while we compute this step.
        float nxz = 0.f, nxr = 0.f, nxh = 0.f, na = 0.f;
        if (t + 1 < tc) {
            if (!FUSED_X) {
                const float* p = xpb + (size_t)(t + 1) * C3;
                nxz = p[j]; nxr = p[64 + j]; nxh = p[128 + j];
            } else {
                na = in[((size_t)b * TT + t0 + t + 1) * FF + j];
            }
        }

        if (FUSED_X) {
            float az2 = bzf, ar2 = brf, ah2 = bh0f;
#pragma unroll
            for (int f = 0; f < 64; ++f) {
                const float s = readlane_f(a0, f);
                az2 = fmaf(s, k_lds[f * C3 + j], az2);
                ar2 = fmaf(s, k_lds[f * C3 + 64 + j], ar2);
                ah2 = fmaf(s, k_lds[f * C3 + 128 + j], ah2);
            }
            xz = az2; xr = ar2; xh = ah2;
        }

        float az = 0.f, ar = 0.f, ah = 0.f;
#pragma unroll
        for (int i = 0; i < 64; ++i) {
            const float hs = readlane_f(h, i);
            az = fmaf(hs, uz[i], az);
            ar = fmaf(hs, ur[i], ar);
            ah = fmaf(hs, uh[i], ah);
        }
        const float z  = fast_sigmoid(xz + az);
        const float r  = fast_sigmoid(xr + ar);
        const float hh = fast_tanh(xh + r * (ah + bh));
        h = fmaf(z, h, (1.0f - z) * hh);

        if (!FUSED_X) { xz = nxz; xr = nxr; xh = nxh; }
        else          { a0 = na; }
    }

    if (!last) {
        hws[(size_t)b * UU + j] = h;
    } else {
        float p = h * dw[j];
#pragma unroll
        for (int o = 32; o > 0; o >>= 1) p += __shfl_down(p, o, 64);
        if (j == 0) out[b] = p + db[0];
    }
}

// ---------------------------------------------------------------------------
extern "C" void kernel_launch(void* const* d_in, const int* in_sizes, int n_in,
                              void* d_out, int out_size, void* d_ws, size_t ws_size,
                              hipStream_t stream) {
    const float* inputs = (const float*)d_in[0];
    const float* kmat   = (const float*)d_in[1];
    const float* rk     = (const float*)d_in[2];
    const float* bias   = (const float*)d_in[3];
    const float* dw     = (const float*)d_in[4];
    const float* db     = (const float*)d_in[5];
    const float* mask   = (const float*)d_in[6];
    float* out = (float*)d_out;

    const size_t h_bytes   = (size_t)BB * UU * sizeof(float);          // 64 KB
    const size_t row_bytes = (size_t)BB * C3 * sizeof(float);          // per timestep

    if (ws_size >= h_bytes + row_bytes) {
        float* hws = (float*)d_ws;
        float* xp  = (float*)((char*)d_ws + h_bytes);
        int tc = (int)((ws_size - h_bytes) / row_bytes);
        if (tc > TT) tc = TT;
        int nch = (TT + tc - 1) / tc;
        tc = (TT + nch - 1) / nch;   // even-ish chunks
        int t0 = 0;
        for (int c = 0; c < nch; ++c) {
            const int cur = (TT - t0) < tc ? (TT - t0) : tc;
            xproj_kernel<<<512, 256, 0, stream>>>(inputs, kmat, bias, xp, t0, cur);
            gru_kernel<false><<<BB, 64, 0, stream>>>(xp, nullptr, nullptr, rk, bias,
                mask, dw, db, hws, out, t0, cur, c == 0 ? 1 : 0, c == nch - 1 ? 1 : 0);
            t0 += cur;
        }
    } else {
        // ws too small: fully fused fallback (x computed on the fly from LDS kernel).
        gru_kernel<true><<<BB, 64, 0, stream>>>(nullptr, inputs, kmat, rk, bias,
            mask, dw, db, nullptr, out, 0, TT, 1, 1);
    }
}

// Round 2
// 1468.374 us; speedup vs baseline: 1.2972x; 1.2972x over previous
//
#include <hip/hip_runtime.h>

// Problem constants (match the reference).
#define BB 256
#define TT 2048
#define FF 64
#define UU 64
#define C3 192        // 3*U
#define CH 32         // timesteps per LDS chunk
#define NCH (TT/CH)   // 64 chunks

__device__ __forceinline__ float readlane_f(float v, int lane) {
    return __int_as_float(__builtin_amdgcn_readlane(__float_as_int(v), lane));
}
// sigmoid/tanh via v_exp/v_rcp; ~1e-6 error, threshold is 2e-2.
__device__ __forceinline__ float fast_sigmoid(float x) {
    return __builtin_amdgcn_rcpf(1.0f + __expf(-x));
}
__device__ __forceinline__ float fast_tanh(float x) {
    return 1.0f - 2.0f * __builtin_amdgcn_rcpf(__expf(2.0f * x) + 1.0f);
}

// Repetition macros: M(I,J) for I,J in 0..7 -> index I*8+J.
#define REP8(M, I) M(I,0) M(I,1) M(I,2) M(I,3) M(I,4) M(I,5) M(I,6) M(I,7)
#define REP64(M) REP8(M,0) REP8(M,1) REP8(M,2) REP8(M,3) REP8(M,4) REP8(M,5) REP8(M,6) REP8(M,7)

// ---------------------------------------------------------------------------
// One block per batch element, 4 waves.
//   wave 0  : serial GRU scan; lane j owns unit j; masked U in 192 NAMED
//             scalar VGPRs (mask in {0,2} -> folding is bit-exact).
//   waves1-3: producer — compute x_proj for the NEXT chunk into LDS
//             (double-buffered). Kernel matrix in 192 named scalar VGPRs.
// Producer path and scan path have disjoint register live ranges, so the
// allocator can overlay them (~215 VGPRs either way).
// Both paths execute exactly 1+NCH barriers in the same order.
// ---------------------------------------------------------------------------
__global__ __launch_bounds__(256, 1)
void gru_fused(const float* __restrict__ in, const float* __restrict__ kmat,
               const float* __restrict__ rk, const float* __restrict__ bias,
               const float* __restrict__ mask, const float* __restrict__ dw,
               const float* __restrict__ db, float* __restrict__ out) {
    __shared__ float xs[2][CH][C3];   // 49,152 B
    const int b    = blockIdx.x;
    const int lane = threadIdx.x & 63;
    const int wv   = threadIdx.x >> 6;

    if (wv == 0) {
        // ------------------------------ scan wave ------------------------------
        const int j = lane;
        const float mz = mask[(size_t)b * UU + j];
        const float mr = mask[(size_t)(BB * UU) + (size_t)b * UU + j];
        const float mh = mask[(size_t)(2 * BB * UU) + (size_t)b * UU + j];

#define DECLU(I,J) float uz_##I##J, ur_##I##J, uh_##I##J;
        REP64(DECLU)
#define INITU(I,J) { const int i_ = (I)*8+(J); \
        uz_##I##J = rk[i_*C3 + j]       * readlane_f(mz, i_); \
        ur_##I##J = rk[i_*C3 + 64 + j]  * readlane_f(mr, i_); \
        uh_##I##J = rk[i_*C3 + 128 + j] * readlane_f(mh, i_); }
        REP64(INITU)

        const float bh = bias[C3 + 128 + j];   // recurrent bias for h-gate (inside r*(.))
        float h = 0.0f;

        __syncthreads();                       // chunk 0 ready
        for (int c = 0; c < NCH; ++c) {
            const float* xb = &xs[c & 1][0][0];
#pragma unroll 1
            for (int t = 0; t < CH; ++t) {
                // x reads issued at top; consumed ~500 cycles later.
                const float xz = xb[t*C3 + j];
                const float xr = xb[t*C3 + 64 + j];
                const float xh = xb[t*C3 + 128 + j];
                float az = 0.0f, ar = 0.0f, ah = bh;
#define STEPU(I,J) { const float hs_ = readlane_f(h, (I)*8+(J)); \
                az = fmaf(hs_, uz_##I##J, az); \
                ar = fmaf(hs_, ur_##I##J, ar); \
                ah = fmaf(hs_, uh_##I##J, ah); }
                REP64(STEPU)
                const float z  = fast_sigmoid(xz + az);
                const float r  = fast_sigmoid(xr + ar);
                const float hh = fast_tanh(fmaf(r, ah, xh));
                h = fmaf(z, h - hh, hh);       // z*h + (1-z)*hh
            }
            __syncthreads();
        }

        // dense head: out[b] = h @ dense_w + dense_b
        float p = h * dw[j];
#pragma unroll
        for (int o = 32; o > 0; o >>= 1) p += __shfl_down(p, o, 64);
        if (j == 0) out[b] = p + db[0];
    } else {
        // ---------------------------- producer waves ---------------------------
#define DECLK(I,J) float kz_##I##J, kr_##I##J, kh_##I##J;
        REP64(DECLK)
#define INITK(I,J) { const int f_ = (I)*8+(J); \
        kz_##I##J = kmat[f_*C3 + lane]; \
        kr_##I##J = kmat[f_*C3 + 64 + lane]; \
        kh_##I##J = kmat[f_*C3 + 128 + lane]; }
        REP64(INITK)
        // Fold input bias + recurrent bias for z,r; h keeps only input bias
        // (its recurrent bias sits inside r*(.) and lives in the scan wave).
        const float bzf = bias[lane]      + bias[C3 + lane];
        const float brf = bias[64 + lane] + bias[C3 + 64 + lane];
        const float bh0 = bias[128 + lane];

        auto fill = [&](int c) {
#pragma unroll 1
            for (int r = wv - 1; r < CH; r += 3) {   // 3 waves split the rows
                const int t = c * CH + r;
                const float a = in[((size_t)b * TT + t) * FF + lane];
                float axz = bzf, axr = brf, axh = bh0;
#define STEPK(I,J) { const float s_ = readlane_f(a, (I)*8+(J)); \
                axz = fmaf(s_, kz_##I##J, axz); \
                axr = fmaf(s_, kr_##I##J, axr); \
                axh = fmaf(s_, kh_##I##J, axh); }
                REP64(STEPK)
                float* o = &xs[c & 1][r][0];
                o[lane]      = axz;
                o[64 + lane] = axr;
                o[128 + lane] = axh;
            }
        };

        fill(0);
        __syncthreads();                       // chunk 0 ready
        for (int c = 0; c < NCH; ++c) {
            if (c + 1 < NCH) fill(c + 1);      // produce ahead into the other buffer
            __syncthreads();
        }
    }
}

// ---------------------------------------------------------------------------
extern "C" void kernel_launch(void* const* d_in, const int* in_sizes, int n_in,
                              void* d_out, int out_size, void* d_ws, size_t ws_size,
                              hipStream_t stream) {
    const float* inputs = (const float*)d_in[0];
    const float* kmat   = (const float*)d_in[1];
    const float* rk     = (const float*)d_in[2];
    const float* bias   = (const float*)d_in[3];
    const float* dw     = (const float*)d_in[4];
    const float* db     = (const float*)d_in[5];
    const float* mask   = (const float*)d_in[6];
    float* out = (float*)d_out;

    gru_fused<<<BB, 256, 0, stream>>>(inputs, kmat, rk, bias, mask, dw, db, out);
}

// Round 3
// 939.574 us; speedup vs baseline: 2.0272x; 1.5628x over previous
//
#include <hip/hip_runtime.h>

// Problem constants (match the reference).
#define BB 256
#define TT 2048
#define FF 64
#define UU 64
#define C3 192   // 3*U

__device__ __forceinline__ float readlane_f(float v, int lane) {
    return __int_as_float(__builtin_amdgcn_readlane(__float_as_int(v), lane));
}
// sigmoid/tanh via v_exp/v_rcp; ~1e-6 error, threshold is 2e-2.
__device__ __forceinline__ float fast_sigmoid(float x) {
    return __builtin_amdgcn_rcpf(1.0f + __expf(-x));
}
__device__ __forceinline__ float fast_tanh(float x) {
    return 1.0f - 2.0f * __builtin_amdgcn_rcpf(__expf(2.0f * x) + 1.0f);
}

#define REP16(M) M(0) M(1) M(2) M(3) M(4) M(5) M(6) M(7) \
                 M(8) M(9) M(10) M(11) M(12) M(13) M(14) M(15)

// ---------------------------------------------------------------------------
// One block per batch element, 4 waves, ALL waves scan cooperatively.
// Wave w owns contraction rows i in [16w, 16w+16):
//   - 16 rows of the recurrent kernel (per-gate), recurrent-dropout mask
//     folded in (mask in {0,2} -> bit-exact),
//   - 16 rows of the input kernel (x_proj fused into the scan).
// 96 resident weights/wave -> stays in architectural VGPRs (no AGPR demotion,
// which is what killed the previous single-scan-wave version).
// Per step: partial sums -> LDS (stride-5, conflict-free) -> 1 barrier ->
// every wave reads the 16 partials and redundantly computes the h update
// (so no broadcast-back). Double-buffered partials => 1 barrier/step.
// h-gate input part (pxh) and recurrent part (pah) kept separate because
// reset_after=True applies r only to the recurrent part.
// ---------------------------------------------------------------------------
__global__ __launch_bounds__(256, 1)
void gru_coop(const float* __restrict__ in, const float* __restrict__ kmat,
              const float* __restrict__ rk, const float* __restrict__ bias,
              const float* __restrict__ mask, const float* __restrict__ dw,
              const float* __restrict__ db, float* __restrict__ out) {
    __shared__ float ps[2][4][64][5];   // [buf][wave][lane][gate(4)+pad] = 10 KB
    const int b    = blockIdx.x;
    const int lane = threadIdx.x & 63;
    const int wv   = threadIdx.x >> 6;
    const int i0   = wv << 4;           // this wave's contraction-row base

    // Dropout masks for this batch row (indexed by contraction index i).
    const float mzv = mask[(size_t)b * UU + lane];
    const float mrv = mask[(size_t)(BB * UU) + (size_t)b * UU + lane];
    const float mhv = mask[(size_t)(2 * BB * UU) + (size_t)b * UU + lane];

    // 96 named resident weights: 16 rows x {Uz,Ur,Uh,Kz,Kr,Kh} (column = lane).
#define DECLW(I) float uz_##I, ur_##I, uh_##I, kz_##I, kr_##I, kh_##I;
    REP16(DECLW)
#define INITW(I) { const int i_ = i0 + (I); \
    uz_##I = rk[i_ * C3 + lane]        * readlane_f(mzv, i_); \
    ur_##I = rk[i_ * C3 + 64 + lane]   * readlane_f(mrv, i_); \
    uh_##I = rk[i_ * C3 + 128 + lane]  * readlane_f(mhv, i_); \
    kz_##I = kmat[i_ * C3 + lane]; \
    kr_##I = kmat[i_ * C3 + 64 + lane]; \
    kh_##I = kmat[i_ * C3 + 128 + lane]; }
    REP16(INITW)

    const float bzf = bias[lane]       + bias[C3 + lane];        // z: in+rec bias
    const float brf = bias[64 + lane]  + bias[C3 + 64 + lane];   // r: in+rec bias
    const float bh0 = bias[128 + lane];                          // h: input bias
    const float bh1 = bias[C3 + 128 + lane];                     // h: recurrent bias

    const float* __restrict__ inb = in + (size_t)b * TT * FF;

    // Rolling 4-deep input prefetch (distance 4..7 steps covers HBM latency).
    float a0 = inb[(size_t)0 * FF + lane];
    float a1 = inb[(size_t)1 * FF + lane];
    float a2 = inb[(size_t)2 * FF + lane];
    float a3 = inb[(size_t)3 * FF + lane];
    float n0, n1, n2, n3;

    float h = 0.0f;

#define ACC1(I, AV) { \
    const float hs_ = readlane_f(h,  i0 + (I)); \
    const float as_ = readlane_f(AV, i0 + (I)); \
    pz  = fmaf(hs_, uz_##I, pz);  pz  = fmaf(as_, kz_##I, pz); \
    pr  = fmaf(hs_, ur_##I, pr);  pr  = fmaf(as_, kr_##I, pr); \
    pah = fmaf(hs_, uh_##I, pah); pxh = fmaf(as_, kh_##I, pxh); }

#define SUBSTEP(S, AV, NV) { \
    const int t_ = (tb << 2) + (S); \
    { const int rn_ = (t_ + 4 < TT) ? (t_ + 4) : (TT - 1); \
      NV = inb[(size_t)rn_ * FF + lane]; } \
    float pz = 0.0f, pr = 0.0f, pxh = 0.0f, pah = 0.0f; \
    REP16(ACC_##AV) \
    float* wp_ = &ps[(S) & 1][wv][lane][0]; \
    wp_[0] = pz; wp_[1] = pr; wp_[2] = pxh; wp_[3] = pah; \
    __syncthreads(); \
    float sz = bzf, sr = brf, sxh = bh0, sah = bh1; \
    { const float* rp_ = &ps[(S) & 1][0][lane][0]; \
      sz += rp_[0];   sr += rp_[1];   sxh += rp_[2];   sah += rp_[3]; \
      sz += rp_[320]; sr += rp_[321]; sxh += rp_[322]; sah += rp_[323]; \
      sz += rp_[640]; sr += rp_[641]; sxh += rp_[642]; sah += rp_[643]; \
      sz += rp_[960]; sr += rp_[961]; sxh += rp_[962]; sah += rp_[963]; } \
    const float z_  = fast_sigmoid(sz); \
    const float r_  = fast_sigmoid(sr); \
    const float hh_ = fast_tanh(fmaf(r_, sah, sxh)); \
    h = fmaf(z_, h - hh_, hh_); }

#define ACC_a0(I) ACC1(I, a0)
#define ACC_a1(I) ACC1(I, a1)
#define ACC_a2(I) ACC1(I, a2)
#define ACC_a3(I) ACC1(I, a3)

#pragma unroll 1
    for (int tb = 0; tb < TT / 4; ++tb) {
        SUBSTEP(0, a0, n0)
        SUBSTEP(1, a1, n1)
        SUBSTEP(2, a2, n2)
        SUBSTEP(3, a3, n3)
        a0 = n0; a1 = n1; a2 = n2; a3 = n3;
    }

    // Dense head: out[b] = h @ dense_w + dense_b (all waves hold identical h).
    if (wv == 0) {
        float p = h * dw[lane];
#pragma unroll
        for (int o = 32; o > 0; o >>= 1) p += __shfl_down(p, o, 64);
        if (lane == 0) out[b] = p + db[0];
    }
}

// ---------------------------------------------------------------------------
extern "C" void kernel_launch(void* const* d_in, const int* in_sizes, int n_in,
                              void* d_out, int out_size, void* d_ws, size_t ws_size,
                              hipStream_t stream) {
    const float* inputs = (const float*)d_in[0];
    const float* kmat   = (const float*)d_in[1];
    const float* rk     = (const float*)d_in[2];
    const float* bias   = (const float*)d_in[3];
    const float* dw     = (const float*)d_in[4];
    const float* db     = (const float*)d_in[5];
    const float* mask   = (const float*)d_in[6];
    float* out = (float*)d_out;

    gru_coop<<<BB, 256, 0, stream>>>(inputs, kmat, rk, bias, mask, dw, db, out);
}